// Round 5
// baseline (25061.780 us; speedup 1.0000x reference)
//
#include <hip/hip_runtime.h>

typedef unsigned int u32;
typedef unsigned short u16;

constexpr int NIN = 10, H = 100, OUTN = 10, NL = 5, NB = 64, T = 2048;

__device__ __forceinline__ float b2f(u16 u){ return __builtin_bit_cast(float, ((u32)u)<<16); }
__device__ __forceinline__ u32 f2bu(float f){
  u32 u = __builtin_bit_cast(u32, f);
  return (u + 0x7fffu + ((u>>16)&1u)) >> 16;  // RNE bf16 (output fallback only)
}
__device__ __forceinline__ float ftanh(float x){
  float e = __expf(x + x);
  return 1.0f - 2.0f/(e + 1.0f);
}

// Two blocks per batch row (grid 128): block b = layers 0..2, block b+64 =
// layers 3..4 + out. Full fp32 everywhere (recurrent noise amplification
// saturates fp16/bf16 internal state at ~5e-2 absmax — rounds 2/3).
// Round 4 lesson: VGPR_Count=84 proved w[100] was in SCRATCH (rolled init
// loops with runtime index); this version force-unrolls all weight init with
// aligned float4/float2 loads so every w[k] index is compile-time constant.
__global__ __launch_bounds__(640, 1)
void rnn5(const void* __restrict__ xg, const void* __restrict__ hprev,
          const void* __restrict__ Wih0, const void* __restrict__ Wih,
          const void* __restrict__ Whh, const void* __restrict__ bih,
          const void* __restrict__ bhh, const void* __restrict__ Wout,
          const void* __restrict__ bout, void* __restrict__ outv,
          float* __restrict__ ring, int* __restrict__ flags, int ringSlots)
{
  __shared__ __align__(16) float hb[3][2][128];   // A: h0,h1,h2 ; B: h3,h4
  __shared__ __align__(16) float part[2][128];    // ih partials
  __shared__ __align__(16) float h2l[2][112];     // B: staged h2
  __shared__ __align__(16) float xst[2][12];      // A: staged x[t] (pad 12)

  const int tid = threadIdx.x, wv = tid>>6, lane = tid&63;
  const bool isA = (blockIdx.x < NB);
  const int b = isA ? (int)blockIdx.x : (int)blockIdx.x - NB;
  const int rmask = ringSlots - 1;
  int* progp = flags + b*32;            // h2 ready-count (A publishes)
  int* consp = flags + NB*32 + b*32;    // h2 consumed-count (B publishes)

  // runtime storage-dtype detection (fp32 confirmed on HW; bf16 kept as fallback)
  bool isf32 = false;
  { const u16* p = (const u16*)Wih0;
    for (int i=0;i<128;++i) if (((p[i]>>7)&0xFF) >= 0x80) isf32 = true; }
  auto ldf = [&](const void* p, size_t i)->float {
    return isf32 ? ((const float*)p)[i] : b2f(((const u16*)p)[i]); };

  // ---- per-wave role setup -------------------------------------------------
  float w[100];
  #pragma unroll
  for (int i=0;i<100;++i) w[i]=0.f;
  float wx[12];
  #pragma unroll
  for (int i=0;i<12;++i) wx[i]=0.f;
  float bias = 0.f;
  int dt = 1<<20, srcL = 0, partIdx = -1, dstL = 0;
  bool srcH2=false, hh=false, hasX=false, ringSt=false, isOut=false;
  const int row = ((wv&1)?64:0) + lane;

  // fully-unrolled register loads (compile-time indices -> stays in VGPRs)
  auto ldrow100 = [&](const void* base, size_t elemOff){
    if (isf32){
      const float4* s4 = (const float4*)((const float*)base + elemOff); // rows 400B apart: 16B-aligned
      #pragma unroll
      for (int c=0;c<25;++c){
        float4 v = s4[c];
        w[4*c+0]=v.x; w[4*c+1]=v.y; w[4*c+2]=v.z; w[4*c+3]=v.w;
      }
    } else {
      const u16* s = (const u16*)base + elemOff;
      #pragma unroll
      for (int k=0;k<100;++k) w[k]=b2f(s[k]);
    }
  };
  auto ldrow10 = [&](const void* base, size_t elemOff){
    if (isf32){
      const float2* s2 = (const float2*)((const float*)base + elemOff); // rows 40B apart: 8B-aligned
      #pragma unroll
      for (int c=0;c<5;++c){ float2 v = s2[c]; wx[2*c]=v.x; wx[2*c+1]=v.y; }
    } else {
      const u16* s = (const u16*)base + elemOff;
      #pragma unroll
      for (int k=0;k<10;++k) wx[k]=b2f(s[k]);
    }
  };

  if (isA){
    if (wv<2){            // L0 hh + x
      dt=0; hh=true; dstL=0; srcL=0; hasX=true;
      if (row<H){
        ldrow100(Whh, (size_t)row*H);
        ldrow10(Wih0, (size_t)row*NIN);
        bias = ldf(bih,row)+ldf(bhh,row);
      }
    } else if (wv<4){     // L1 ih (Wih[0])
      dt=1; srcL=0; partIdx=0;
      if (row<H) ldrow100(Wih, (size_t)row*H);
    } else if (wv<6){     // L1 hh
      dt=1; hh=true; dstL=1; srcL=1; partIdx=0;
      if (row<H){
        ldrow100(Whh, (size_t)1*H*H + (size_t)row*H);
        bias = ldf(bih,1*H+row)+ldf(bhh,1*H+row);
      }
    } else if (wv<8){     // L2 ih (Wih[1])
      dt=2; srcL=1; partIdx=1;
      if (row<H) ldrow100(Wih, (size_t)1*H*H + (size_t)row*H);
    } else {              // L2 hh + ring store
      dt=2; hh=true; dstL=2; srcL=2; partIdx=1; ringSt=true;
      if (row<H){
        ldrow100(Whh, (size_t)2*H*H + (size_t)row*H);
        bias = ldf(bih,2*H+row)+ldf(bhh,2*H+row);
      }
    }
  } else {
    if (wv<2){            // L3 ih (Wih[2], src = staged h2)
      dt=0; srcH2=true; partIdx=0;
      if (row<H) ldrow100(Wih, (size_t)2*H*H + (size_t)row*H);
    } else if (wv<4){     // L3 hh
      dt=0; hh=true; dstL=0; srcL=0; partIdx=0;
      if (row<H){
        ldrow100(Whh, (size_t)3*H*H + (size_t)row*H);
        bias = ldf(bih,3*H+row)+ldf(bhh,3*H+row);
      }
    } else if (wv<6){     // L4 ih (Wih[3])
      dt=1; srcL=0; partIdx=1;
      if (row<H) ldrow100(Wih, (size_t)3*H*H + (size_t)row*H);
    } else if (wv<8){     // L4 hh
      dt=1; hh=true; dstL=1; srcL=1; partIdx=1;
      if (row<H){
        ldrow100(Whh, (size_t)4*H*H + (size_t)row*H);
        bias = ldf(bih,4*H+row)+ldf(bhh,4*H+row);
      }
    } else if (wv==8){    // out projection
      dt=2; isOut=true; srcL=1;
      if (lane<OUTN){
        ldrow100(Wout, (size_t)lane*H);
        bias = ldf(bout,lane);
      }
    }                      // wv9: idle (dt huge)
  }

  // ---- LDS init ------------------------------------------------------------
  if (tid < 3*128){
    int l = tid>>7, r = tid&127;
    bool use = isA ? true : (l<2);
    if (use){
      int gl = isA ? l : (l+3);
      float v = 0.f;
      if (r<H) v = ldf(hprev, ((size_t)gl*NB+b)*H + r);
      hb[l][1][r] = v;  hb[l][0][r] = 0.f;
    }
  }
  if (isA && wv==0){
    if (lane<NIN){
      size_t x0 = (size_t)b*T*NIN;
      xst[0][lane] = ldf(xg, x0+lane);
      xst[1][lane] = ldf(xg, x0+NIN+lane);
    } else if (lane<12){
      xst[0][lane]=0.f; xst[1][lane]=0.f;
    }
  }
  if (!isA && wv==8){     // pre-stage h2[0]
    while (__hip_atomic_load(progp, __ATOMIC_ACQUIRE, __HIP_MEMORY_SCOPE_AGENT) < 1)
      __builtin_amdgcn_s_sleep(2);
    if (lane<28){
      size_t base = (size_t)(b*ringSlots)*112;
      ((float4*)h2l[0])[lane] = ((const float4*)(ring+base))[lane];
    }
    if (lane==0)
      __hip_atomic_store(consp, 1, __ATOMIC_RELEASE, __HIP_MEMORY_SCOPE_AGENT);
  }
  __syncthreads();

  // ---- main pipelined loop -------------------------------------------------
  float yreg[8];
  #pragma unroll
  for (int i=0;i<8;++i) yreg[i]=0.f;
  const size_t yBase  = (size_t)b*T*OUTN;
  const size_t hfBase = (size_t)NB*T*OUTN;
  float* outf = (float*)outv;  u16* outh = (u16*)outv;
  float xr = 0.f;

  for (int s=0; s<=T+1; ++s){
    const int t = s - dt;
    const bool act = (t>=0) && (t<T);
    float a = 0.f;

    if (isA && wv==0){                       // backpressure + publish
      int t2 = s-2;
      if (t2 >= ringSlots){
        while (__hip_atomic_load(consp, __ATOMIC_ACQUIRE, __HIP_MEMORY_SCOPE_AGENT)
               < t2 - ringSlots + 1)
          __builtin_amdgcn_s_sleep(2);
      }
      if (s>=3 && lane==0)
        __hip_atomic_store(progp, s-2, __ATOMIC_RELEASE, __HIP_MEMORY_SCOPE_AGENT);
    }

    if (act){
      const int slot = hh ? ((t&1)^1) : (t&1);
      const float* hsrc = srcH2 ? h2l[slot] : hb[srcL][slot];
      const float4* h4p = (const float4*)hsrc;
      float a0=bias, a1=0.f, a2=0.f, a3=0.f;
      #pragma unroll
      for (int c=0;c<25;++c){
        float4 hv = h4p[c];                  // broadcast ds_read_b128
        a0 = __builtin_fmaf(w[4*c+0], hv.x, a0);
        a1 = __builtin_fmaf(w[4*c+1], hv.y, a1);
        a2 = __builtin_fmaf(w[4*c+2], hv.z, a2);
        a3 = __builtin_fmaf(w[4*c+3], hv.w, a3);
      }
      if (hasX){
        const float4* xp4 = (const float4*)xst[t&1];
        #pragma unroll
        for (int c=0;c<3;++c){
          float4 xv = xp4[c];
          a0 = __builtin_fmaf(wx[4*c+0], xv.x, a0);
          a1 = __builtin_fmaf(wx[4*c+1], xv.y, a1);
          a2 = __builtin_fmaf(wx[4*c+2], xv.z, a2);
          a3 = __builtin_fmaf(wx[4*c+3], xv.w, a3);
        }
      }
      a = (a0+a1)+(a2+a3);
      if (partIdx>=0 && !hh) part[partIdx][row] = a;
    }

    if (!isA && wv==8 && (s+1)<T){           // poll + stage h2[s+1]
      while (__hip_atomic_load(progp, __ATOMIC_ACQUIRE, __HIP_MEMORY_SCOPE_AGENT) < s+2)
        __builtin_amdgcn_s_sleep(2);
      if (lane<28){
        size_t base = (size_t)(b*ringSlots + ((s+1)&rmask))*112;
        ((float4*)h2l[(s+1)&1])[lane] = ((const float4*)(ring+base))[lane];
      }
      if (lane==0)
        __hip_atomic_store(consp, s+2, __ATOMIC_RELEASE, __HIP_MEMORY_SCOPE_AGENT);
    }
    if (isA && wv==0 && lane<NIN && (s+2)<T){ // x prefetch (2-step lookahead)
      size_t xi = (size_t)b*T*NIN + (size_t)(s+2)*NIN + lane;
      xr = isf32 ? ((const float*)xg)[xi] : b2f(((const u16*)xg)[xi]);
    }
    __syncthreads();

    // phase B: finalize / output
    if (act && hh){
      float v = a;
      if (partIdx>=0) v += part[partIdx][row];
      float hval = ftanh(v);
      hb[dstL][t&1][row] = hval;
      if (ringSt && row<H)
        ring[(size_t)(b*ringSlots + (t&rmask))*112 + row] = hval;
      if (t==T-1 && row<H){
        int gl = isA ? dstL : dstL+3;
        size_t o = hfBase + ((size_t)gl*NB + b)*H + row;
        if (isf32) outf[o]=hval; else outh[o]=(u16)f2bu(hval);
      }
    }
    if (isOut && act && lane<OUTN){
      yreg[t&7] = a;
      if ((t&7)==7){
        size_t basei = yBase + (size_t)(t-7)*OUTN + lane;
        if (isf32){
          #pragma unroll
          for (int q=0;q<8;++q) outf[basei+(size_t)q*OUTN] = yreg[q];
        } else {
          #pragma unroll
          for (int q=0;q<8;++q) outh[basei+(size_t)q*OUTN] = (u16)f2bu(yreg[q]);
        }
      }
    }
    if (isA && wv==0 && lane<NIN && (s+2)<T)
      xst[s&1][lane] = xr;                   // slot s&1 == (s+2)&1
    __syncthreads();
  }
  if (isA && wv==0 && lane==0)
    __hip_atomic_store(progp, T, __ATOMIC_RELEASE, __HIP_MEMORY_SCOPE_AGENT);
}

extern "C" void kernel_launch(void* const* d_in, const int* in_sizes, int n_in,
                              void* d_out, int out_size, void* d_ws, size_t ws_size,
                              hipStream_t stream){
  int* flags = (int*)d_ws;                       // 2*64*32 ints = 16 KB, 0xAA-poisoned => negative
  size_t flagBytes = (size_t)2*NB*32*sizeof(int);
  float* ring = (float*)((char*)d_ws + flagBytes);
  size_t availF = ws_size > flagBytes ? (ws_size - flagBytes)/sizeof(float) : 0;
  int slots = 64;
  while (slots > 2 && (size_t)NB*slots*112 > availF) slots >>= 1;
  rnn5<<<dim3(2*NB), dim3(640), 0, stream>>>(
    d_in[0], d_in[1], d_in[2], d_in[3], d_in[4],
    d_in[5], d_in[6], d_in[7], d_in[8], d_out,
    ring, flags, slots);
}

// Round 6
// 16816.875 us; speedup vs baseline: 1.4903x; 1.4903x over previous
//
#include <hip/hip_runtime.h>

typedef unsigned int u32;
typedef unsigned short u16;

constexpr int NIN = 10, H = 100, OUTN = 10, NL = 5, NB = 64, T = 2048;

__device__ __forceinline__ float ftanh(float x){
  float e = __expf(x + x);
  return 1.0f - 2.0f/(e + 1.0f);
}

// Two blocks per batch row (grid 128): block b = layers 0..2, block b+64 =
// layers 3..4 + out. Full fp32 (recurrent noise amplification saturates any
// fp16/bf16 internal state at ~5e-2 absmax — rounds 2/3). Storage dtype is
// fp32 (HW-confirmed rounds 2-5).
// Round 4: VGPR=84 — rolled init loops put w[100] in scratch.
// Round 5: VGPR=60, FETCH=5.3GB — by-ref lambda escaped the alloca; scratch
// reloads in the hot loop. This round: NO local weight array at all — 25
// named float4 registers, one predicated load site, no lambdas.
__global__ __launch_bounds__(640, 1)
void rnn5(const float* __restrict__ xg, const float* __restrict__ hprev,
          const float* __restrict__ Wih0, const float* __restrict__ Wih,
          const float* __restrict__ Whh, const float* __restrict__ bih,
          const float* __restrict__ bhh, const float* __restrict__ Wout,
          const float* __restrict__ bout, float* __restrict__ outf,
          float* __restrict__ ring, int* __restrict__ flags, int ringSlots)
{
  __shared__ __align__(16) float hb[3][2][128];   // A: h0,h1,h2 ; B: h3,h4
  __shared__ __align__(16) float part[2][128];    // ih partials
  __shared__ __align__(16) float h2l[2][112];     // B: staged h2
  __shared__ __align__(16) float xst[2][12];      // A: staged x[t]

  const int tid = threadIdx.x, wv = tid>>6, lane = tid&63;
  const bool isA = (blockIdx.x < NB);
  const int b = isA ? (int)blockIdx.x : (int)blockIdx.x - NB;
  const int rmask = ringSlots - 1;
  int* progp = flags + b*32;            // h2 ready-count (A publishes)
  int* consp = flags + NB*32 + b*32;    // h2 consumed-count (B publishes)
  const int row = ((wv&1)?64:0) + lane;

  // ---- role setup: pick weight-row pointer, then ONE load site ------------
  float4 W0={0,0,0,0},W1=W0,W2=W0,W3=W0,W4=W0,W5=W0,W6=W0,W7=W0,W8=W0,W9=W0,
         W10=W0,W11=W0,W12=W0,W13=W0,W14=W0,W15=W0,W16=W0,W17=W0,W18=W0,
         W19=W0,W20=W0,W21=W0,W22=W0,W23=W0,W24=W0;
  float2 U0={0,0},U1=U0,U2=U0,U3=U0,U4=U0;
  float bias = 0.f;
  int dt = 1<<20, srcL = 0, partIdx = -1, dstL = 0;
  bool srcH2=false, hh=false, hasX=false, ringSt=false, isOut=false;
  const float4* wsrc = nullptr;
  const float2* usrc = nullptr;

  if (isA){
    if (wv<2){            // L0 hh + x
      dt=0; hh=true; dstL=0; srcL=0; hasX=true;
      if (row<H){
        wsrc = (const float4*)(Whh + (size_t)row*H);
        usrc = (const float2*)(Wih0 + (size_t)row*NIN);
        bias = bih[row] + bhh[row];
      }
    } else if (wv<4){     // L1 ih (Wih[0])
      dt=1; srcL=0; partIdx=0;
      if (row<H) wsrc = (const float4*)(Wih + (size_t)row*H);
    } else if (wv<6){     // L1 hh
      dt=1; hh=true; dstL=1; srcL=1; partIdx=0;
      if (row<H){
        wsrc = (const float4*)(Whh + (size_t)1*H*H + (size_t)row*H);
        bias = bih[1*H+row] + bhh[1*H+row];
      }
    } else if (wv<8){     // L2 ih (Wih[1])
      dt=2; srcL=1; partIdx=1;
      if (row<H) wsrc = (const float4*)(Wih + (size_t)1*H*H + (size_t)row*H);
    } else {              // L2 hh + ring store
      dt=2; hh=true; dstL=2; srcL=2; partIdx=1; ringSt=true;
      if (row<H){
        wsrc = (const float4*)(Whh + (size_t)2*H*H + (size_t)row*H);
        bias = bih[2*H+row] + bhh[2*H+row];
      }
    }
  } else {
    if (wv<2){            // L3 ih (Wih[2], src = staged h2)
      dt=0; srcH2=true; partIdx=0;
      if (row<H) wsrc = (const float4*)(Wih + (size_t)2*H*H + (size_t)row*H);
    } else if (wv<4){     // L3 hh
      dt=0; hh=true; dstL=0; srcL=0; partIdx=0;
      if (row<H){
        wsrc = (const float4*)(Whh + (size_t)3*H*H + (size_t)row*H);
        bias = bih[3*H+row] + bhh[3*H+row];
      }
    } else if (wv<6){     // L4 ih (Wih[3])
      dt=1; srcL=0; partIdx=1;
      if (row<H) wsrc = (const float4*)(Wih + (size_t)3*H*H + (size_t)row*H);
    } else if (wv<8){     // L4 hh
      dt=1; hh=true; dstL=1; srcL=1; partIdx=1;
      if (row<H){
        wsrc = (const float4*)(Whh + (size_t)4*H*H + (size_t)row*H);
        bias = bih[4*H+row] + bhh[4*H+row];
      }
    } else if (wv==8){    // out projection
      dt=2; isOut=true; srcL=1;
      if (lane<OUTN){
        wsrc = (const float4*)(Wout + (size_t)lane*H);
        bias = bout[lane];
      }
    }                     // wv9: idle (barriers only)
  }

  if (wsrc){              // single load site -> stays in VGPRs
    W0 =wsrc[0];  W1 =wsrc[1];  W2 =wsrc[2];  W3 =wsrc[3];  W4 =wsrc[4];
    W5 =wsrc[5];  W6 =wsrc[6];  W7 =wsrc[7];  W8 =wsrc[8];  W9 =wsrc[9];
    W10=wsrc[10]; W11=wsrc[11]; W12=wsrc[12]; W13=wsrc[13]; W14=wsrc[14];
    W15=wsrc[15]; W16=wsrc[16]; W17=wsrc[17]; W18=wsrc[18]; W19=wsrc[19];
    W20=wsrc[20]; W21=wsrc[21]; W22=wsrc[22]; W23=wsrc[23]; W24=wsrc[24];
  }
  if (usrc){
    U0=usrc[0]; U1=usrc[1]; U2=usrc[2]; U3=usrc[3]; U4=usrc[4];
  }

  // ---- LDS init ------------------------------------------------------------
  if (tid < 3*128){
    int l = tid>>7, r = tid&127;
    bool use = isA ? true : (l<2);
    if (use){
      int gl = isA ? l : (l+3);
      float v = 0.f;
      if (r<H) v = hprev[((size_t)gl*NB+b)*H + r];
      hb[l][1][r] = v;  hb[l][0][r] = 0.f;
    }
  }
  if (isA && wv==0){
    if (lane<NIN){
      size_t x0 = (size_t)b*T*NIN;
      xst[0][lane] = xg[x0+lane];
      xst[1][lane] = xg[x0+NIN+lane];
    } else if (lane<12){
      xst[0][lane]=0.f; xst[1][lane]=0.f;
    }
  }
  if (!isA && wv==8){     // pre-stage h2[0]
    while (__hip_atomic_load(progp, __ATOMIC_ACQUIRE, __HIP_MEMORY_SCOPE_AGENT) < 1)
      __builtin_amdgcn_s_sleep(2);
    if (lane<28){
      size_t base = (size_t)(b*ringSlots)*112;
      ((float4*)h2l[0])[lane] = ((const float4*)(ring+base))[lane];
    }
    if (lane==0)
      __hip_atomic_store(consp, 1, __ATOMIC_RELEASE, __HIP_MEMORY_SCOPE_AGENT);
  }
  __syncthreads();

  // ---- main pipelined loop -------------------------------------------------
  float y0=0,y1=0,y2=0,y3=0,y4=0,y5=0,y6=0,y7=0;
  const size_t yBase  = (size_t)b*T*OUTN;
  const size_t hfBase = (size_t)NB*T*OUTN;
  float xr = 0.f;

  for (int s=0; s<=T+1; ++s){
    const int t = s - dt;
    const bool act = (t>=0) && (t<T);
    float a = 0.f;

    if (isA && wv==0){                       // backpressure + publish
      int t2 = s-2;
      if (t2 >= ringSlots){
        while (__hip_atomic_load(consp, __ATOMIC_ACQUIRE, __HIP_MEMORY_SCOPE_AGENT)
               < t2 - ringSlots + 1)
          __builtin_amdgcn_s_sleep(2);
      }
      if (s>=3 && lane==0)
        __hip_atomic_store(progp, s-2, __ATOMIC_RELEASE, __HIP_MEMORY_SCOPE_AGENT);
    }

    if (act){
      const int slot = hh ? ((t&1)^1) : (t&1);
      const float4* h4p = srcH2 ? (const float4*)h2l[slot]
                                : (const float4*)hb[srcL][slot];
      float a0=bias, a1=0.f, a2=0.f, a3=0.f;
#define MV(i,Wn) { float4 hv=h4p[i]; \
      a0=__builtin_fmaf(Wn.x,hv.x,a0); a1=__builtin_fmaf(Wn.y,hv.y,a1); \
      a2=__builtin_fmaf(Wn.z,hv.z,a2); a3=__builtin_fmaf(Wn.w,hv.w,a3); }
      MV(0,W0)  MV(1,W1)  MV(2,W2)  MV(3,W3)  MV(4,W4)
      MV(5,W5)  MV(6,W6)  MV(7,W7)  MV(8,W8)  MV(9,W9)
      MV(10,W10) MV(11,W11) MV(12,W12) MV(13,W13) MV(14,W14)
      MV(15,W15) MV(16,W16) MV(17,W17) MV(18,W18) MV(19,W19)
      MV(20,W20) MV(21,W21) MV(22,W22) MV(23,W23) MV(24,W24)
#undef MV
      if (hasX){
        const float2* xp2 = (const float2*)xst[t&1];
#define MX(i,Un) { float2 xv=xp2[i]; \
      a0=__builtin_fmaf(Un.x,xv.x,a0); a1=__builtin_fmaf(Un.y,xv.y,a1); }
        MX(0,U0) MX(1,U1) MX(2,U2) MX(3,U3) MX(4,U4)
#undef MX
      }
      a = (a0+a1)+(a2+a3);
      if (partIdx>=0 && !hh) part[partIdx][row] = a;
    }

    if (!isA && wv==8 && (s+1)<T){           // poll + stage h2[s+1]
      while (__hip_atomic_load(progp, __ATOMIC_ACQUIRE, __HIP_MEMORY_SCOPE_AGENT) < s+2)
        __builtin_amdgcn_s_sleep(2);
      if (lane<28){
        size_t base = (size_t)(b*ringSlots + ((s+1)&rmask))*112;
        ((float4*)h2l[(s+1)&1])[lane] = ((const float4*)(ring+base))[lane];
      }
      if (lane==0)
        __hip_atomic_store(consp, s+2, __ATOMIC_RELEASE, __HIP_MEMORY_SCOPE_AGENT);
    }
    if (isA && wv==0 && lane<NIN && (s+2)<T)  // x prefetch (2-step lookahead)
      xr = xg[(size_t)b*T*NIN + (size_t)(s+2)*NIN + lane];
    __syncthreads();

    // phase B: finalize / output
    if (act && hh){
      float v = a;
      if (partIdx>=0) v += part[partIdx][row];
      float hval = ftanh(v);
      hb[dstL][t&1][row] = hval;
      if (ringSt && row<H)
        ring[(size_t)(b*ringSlots + (t&rmask))*112 + row] = hval;
      if (t==T-1 && row<H){
        int gl = isA ? dstL : dstL+3;
        outf[hfBase + ((size_t)gl*NB + b)*H + row] = hval;
      }
    }
    if (isOut && act && lane<OUTN){
      const int ph = t&7;                     // named-reg rotation (no alloca)
      y0 = (ph==0)?a:y0;  y1 = (ph==1)?a:y1;
      y2 = (ph==2)?a:y2;  y3 = (ph==3)?a:y3;
      y4 = (ph==4)?a:y4;  y5 = (ph==5)?a:y5;
      y6 = (ph==6)?a:y6;  y7 = (ph==7)?a:y7;
      if (ph==7){
        size_t basei = yBase + (size_t)(t-7)*OUTN + lane;
        outf[basei+0*OUTN]=y0; outf[basei+1*OUTN]=y1;
        outf[basei+2*OUTN]=y2; outf[basei+3*OUTN]=y3;
        outf[basei+4*OUTN]=y4; outf[basei+5*OUTN]=y5;
        outf[basei+6*OUTN]=y6; outf[basei+7*OUTN]=y7;
      }
    }
    if (isA && wv==0 && lane<NIN && (s+2)<T)
      xst[s&1][lane] = xr;                   // slot s&1 == (s+2)&1
    __syncthreads();
  }
  if (isA && wv==0 && lane==0)
    __hip_atomic_store(progp, T, __ATOMIC_RELEASE, __HIP_MEMORY_SCOPE_AGENT);
}

extern "C" void kernel_launch(void* const* d_in, const int* in_sizes, int n_in,
                              void* d_out, int out_size, void* d_ws, size_t ws_size,
                              hipStream_t stream){
  int* flags = (int*)d_ws;                       // 0xAA poison => negative ints
  size_t flagBytes = (size_t)2*NB*32*sizeof(int);
  float* ring = (float*)((char*)d_ws + flagBytes);
  size_t availF = ws_size > flagBytes ? (ws_size - flagBytes)/sizeof(float) : 0;
  int slots = 64;
  while (slots > 2 && (size_t)NB*slots*112 > availF) slots >>= 1;
  rnn5<<<dim3(2*NB), dim3(640), 0, stream>>>(
    (const float*)d_in[0], (const float*)d_in[1], (const float*)d_in[2],
    (const float*)d_in[3], (const float*)d_in[4], (const float*)d_in[5],
    (const float*)d_in[6], (const float*)d_in[7], (const float*)d_in[8],
    (float*)d_out, ring, flags, slots);
}

// Round 7
// 5828.624 us; speedup vs baseline: 4.2998x; 2.8852x over previous
//
#include <hip/hip_runtime.h>

typedef unsigned int u32;
typedef unsigned short u16;
typedef float f32x2 __attribute__((ext_vector_type(2)));

constexpr int NIN = 10, H = 100, OUTN = 10, NL = 5, NB = 64, T = 2048;

__device__ __forceinline__ float ftanh(float x){
  float e = __expf(x + x);
  return 1.0f - 2.0f/(e + 1.0f);
}

// Two blocks per batch row (grid 128): block b = layers 0..2, block b+64 =
// layers 3..4 + out. Full fp32 (bf16/fp16 state saturates at ~5e-2 absmax).
// R4: rolled init -> scratch. R5: lambda escape -> scratch (FETCH 5.3GB).
// R6: VGPR=84, WRITE 3.2GB -> allocator rematerialized the (legal) weight
// loads inside the loop + per-iter spill flushed by agent-scope fences.
// This round: 50 named f32x2 weights made OPAQUE via empty asm ("+v") so
// remat is impossible; inner loop uses v_pk_fma_f32 (2 FMA/instr).
__global__ __launch_bounds__(640, 1)
void rnn5(const float* __restrict__ xg, const float* __restrict__ hprev,
          const float* __restrict__ Wih0, const float* __restrict__ Wih,
          const float* __restrict__ Whh, const float* __restrict__ bih,
          const float* __restrict__ bhh, const float* __restrict__ Wout,
          const float* __restrict__ bout, float* __restrict__ outf,
          float* __restrict__ ring, int* __restrict__ flags, int ringSlots)
{
  __shared__ __align__(16) float hb[3][2][128];   // A: h0,h1,h2 ; B: h3,h4
  __shared__ __align__(16) float part[2][128];    // ih partials
  __shared__ __align__(16) float h2l[2][112];     // B: staged h2
  __shared__ __align__(16) float xst[2][12];      // A: staged x[t]

  const int tid = threadIdx.x, wv = tid>>6, lane = tid&63;
  const bool isA = (blockIdx.x < NB);
  const int b = isA ? (int)blockIdx.x : (int)blockIdx.x - NB;
  const int rmask = ringSlots - 1;
  int* progp = flags + b*32;            // h2 ready-count (A publishes)
  int* consp = flags + NB*32 + b*32;    // h2 consumed-count (B publishes)
  const int row = ((wv&1)?64:0) + lane;

  // ---- role setup ----------------------------------------------------------
  f32x2 P0={0,0},P1=P0,P2=P0,P3=P0,P4=P0,P5=P0,P6=P0,P7=P0,P8=P0,P9=P0,
        P10=P0,P11=P0,P12=P0,P13=P0,P14=P0,P15=P0,P16=P0,P17=P0,P18=P0,P19=P0,
        P20=P0,P21=P0,P22=P0,P23=P0,P24=P0,P25=P0,P26=P0,P27=P0,P28=P0,P29=P0,
        P30=P0,P31=P0,P32=P0,P33=P0,P34=P0,P35=P0,P36=P0,P37=P0,P38=P0,P39=P0,
        P40=P0,P41=P0,P42=P0,P43=P0,P44=P0,P45=P0,P46=P0,P47=P0,P48=P0,P49=P0;
  f32x2 U0={0,0},U1=U0,U2=U0,U3=U0,U4=U0;
  float bias = 0.f;
  int dt = 1<<20, srcL = 0, partIdx = -1, dstL = 0;
  bool srcH2=false, hh=false, hasX=false, ringSt=false, isOut=false;
  const f32x2* wsrc = nullptr;
  const f32x2* usrc = nullptr;

  if (isA){
    if (wv<2){            // L0 hh + x
      dt=0; hh=true; dstL=0; srcL=0; hasX=true;
      if (row<H){
        wsrc = (const f32x2*)(Whh + (size_t)row*H);
        usrc = (const f32x2*)(Wih0 + (size_t)row*NIN);
        bias = bih[row] + bhh[row];
      }
    } else if (wv<4){     // L1 ih (Wih[0])
      dt=1; srcL=0; partIdx=0;
      if (row<H) wsrc = (const f32x2*)(Wih + (size_t)row*H);
    } else if (wv<6){     // L1 hh
      dt=1; hh=true; dstL=1; srcL=1; partIdx=0;
      if (row<H){
        wsrc = (const f32x2*)(Whh + (size_t)1*H*H + (size_t)row*H);
        bias = bih[1*H+row] + bhh[1*H+row];
      }
    } else if (wv<8){     // L2 ih (Wih[1])
      dt=2; srcL=1; partIdx=1;
      if (row<H) wsrc = (const f32x2*)(Wih + (size_t)1*H*H + (size_t)row*H);
    } else {              // L2 hh + ring store
      dt=2; hh=true; dstL=2; srcL=2; partIdx=1; ringSt=true;
      if (row<H){
        wsrc = (const f32x2*)(Whh + (size_t)2*H*H + (size_t)row*H);
        bias = bih[2*H+row] + bhh[2*H+row];
      }
    }
  } else {
    if (wv<2){            // L3 ih (Wih[2], src = staged h2)
      dt=0; srcH2=true; partIdx=0;
      if (row<H) wsrc = (const f32x2*)(Wih + (size_t)2*H*H + (size_t)row*H);
    } else if (wv<4){     // L3 hh
      dt=0; hh=true; dstL=0; srcL=0; partIdx=0;
      if (row<H){
        wsrc = (const f32x2*)(Whh + (size_t)3*H*H + (size_t)row*H);
        bias = bih[3*H+row] + bhh[3*H+row];
      }
    } else if (wv<6){     // L4 ih (Wih[3])
      dt=1; srcL=0; partIdx=1;
      if (row<H) wsrc = (const f32x2*)(Wih + (size_t)3*H*H + (size_t)row*H);
    } else if (wv<8){     // L4 hh
      dt=1; hh=true; dstL=1; srcL=1; partIdx=1;
      if (row<H){
        wsrc = (const f32x2*)(Whh + (size_t)4*H*H + (size_t)row*H);
        bias = bih[4*H+row] + bhh[4*H+row];
      }
    } else if (wv==8){    // out projection
      dt=2; isOut=true; srcL=1;
      if (lane<OUTN){
        wsrc = (const f32x2*)(Wout + (size_t)lane*H);
        bias = bout[lane];
      }
    }                     // wv9: idle (barriers only)
  }

  if (wsrc){              // one load site
    P0 =wsrc[0];  P1 =wsrc[1];  P2 =wsrc[2];  P3 =wsrc[3];  P4 =wsrc[4];
    P5 =wsrc[5];  P6 =wsrc[6];  P7 =wsrc[7];  P8 =wsrc[8];  P9 =wsrc[9];
    P10=wsrc[10]; P11=wsrc[11]; P12=wsrc[12]; P13=wsrc[13]; P14=wsrc[14];
    P15=wsrc[15]; P16=wsrc[16]; P17=wsrc[17]; P18=wsrc[18]; P19=wsrc[19];
    P20=wsrc[20]; P21=wsrc[21]; P22=wsrc[22]; P23=wsrc[23]; P24=wsrc[24];
    P25=wsrc[25]; P26=wsrc[26]; P27=wsrc[27]; P28=wsrc[28]; P29=wsrc[29];
    P30=wsrc[30]; P31=wsrc[31]; P32=wsrc[32]; P33=wsrc[33]; P34=wsrc[34];
    P35=wsrc[35]; P36=wsrc[36]; P37=wsrc[37]; P38=wsrc[38]; P39=wsrc[39];
    P40=wsrc[40]; P41=wsrc[41]; P42=wsrc[42]; P43=wsrc[43]; P44=wsrc[44];
    P45=wsrc[45]; P46=wsrc[46]; P47=wsrc[47]; P48=wsrc[48]; P49=wsrc[49];
  }
  if (usrc){ U0=usrc[0]; U1=usrc[1]; U2=usrc[2]; U3=usrc[3]; U4=usrc[4]; }

  // Opacity barriers: asm-defined values cannot be rematerialized; pressure
  // (~140) < 168-VGPR budget (640 thr -> 3 waves/EU) so they stay resident.
  asm volatile("" : "+v"(P0),"+v"(P1),"+v"(P2),"+v"(P3),"+v"(P4),
                    "+v"(P5),"+v"(P6),"+v"(P7),"+v"(P8),"+v"(P9));
  asm volatile("" : "+v"(P10),"+v"(P11),"+v"(P12),"+v"(P13),"+v"(P14),
                    "+v"(P15),"+v"(P16),"+v"(P17),"+v"(P18),"+v"(P19));
  asm volatile("" : "+v"(P20),"+v"(P21),"+v"(P22),"+v"(P23),"+v"(P24),
                    "+v"(P25),"+v"(P26),"+v"(P27),"+v"(P28),"+v"(P29));
  asm volatile("" : "+v"(P30),"+v"(P31),"+v"(P32),"+v"(P33),"+v"(P34),
                    "+v"(P35),"+v"(P36),"+v"(P37),"+v"(P38),"+v"(P39));
  asm volatile("" : "+v"(P40),"+v"(P41),"+v"(P42),"+v"(P43),"+v"(P44),
                    "+v"(P45),"+v"(P46),"+v"(P47),"+v"(P48),"+v"(P49));
  asm volatile("" : "+v"(U0),"+v"(U1),"+v"(U2),"+v"(U3),"+v"(U4));

  // ---- LDS init ------------------------------------------------------------
  if (tid < 3*128){
    int l = tid>>7, r = tid&127;
    bool use = isA ? true : (l<2);
    if (use){
      int gl = isA ? l : (l+3);
      float v = 0.f;
      if (r<H) v = hprev[((size_t)gl*NB+b)*H + r];
      hb[l][1][r] = v;  hb[l][0][r] = 0.f;
    }
  }
  if (isA && wv==0){
    if (lane<NIN){
      size_t x0 = (size_t)b*T*NIN;
      xst[0][lane] = xg[x0+lane];
      xst[1][lane] = xg[x0+NIN+lane];
    } else if (lane<12){
      xst[0][lane]=0.f; xst[1][lane]=0.f;
    }
  }
  if (!isA && wv==8){     // pre-stage h2[0]
    while (__hip_atomic_load(progp, __ATOMIC_ACQUIRE, __HIP_MEMORY_SCOPE_AGENT) < 1)
      __builtin_amdgcn_s_sleep(2);
    if (lane<28){
      size_t base = (size_t)(b*ringSlots)*112;
      ((float4*)h2l[0])[lane] = ((const float4*)(ring+base))[lane];
    }
    if (lane==0)
      __hip_atomic_store(consp, 1, __ATOMIC_RELEASE, __HIP_MEMORY_SCOPE_AGENT);
  }
  __syncthreads();

  // ---- main pipelined loop -------------------------------------------------
  float y0=0,y1=0,y2=0,y3=0,y4=0,y5=0,y6=0,y7=0;
  const size_t yBase  = (size_t)b*T*OUTN;
  const size_t hfBase = (size_t)NB*T*OUTN;
  float xr = 0.f;

  for (int s=0; s<=T+1; ++s){
    const int t = s - dt;
    const bool act = (t>=0) && (t<T);
    float a = 0.f;

    if (isA && wv==0){                       // backpressure + publish
      int t2 = s-2;
      if (t2 >= ringSlots){
        while (__hip_atomic_load(consp, __ATOMIC_ACQUIRE, __HIP_MEMORY_SCOPE_AGENT)
               < t2 - ringSlots + 1)
          __builtin_amdgcn_s_sleep(2);
      }
      if (s>=3 && lane==0)
        __hip_atomic_store(progp, s-2, __ATOMIC_RELEASE, __HIP_MEMORY_SCOPE_AGENT);
    }

    if (act){
      const int slot = hh ? ((t&1)^1) : (t&1);
      const float4* h4p = srcH2 ? (const float4*)h2l[slot]
                                : (const float4*)hb[srcL][slot];
      f32x2 A0, A1={0,0}, A2={0,0}, A3={0,0};
      A0.x = bias; A0.y = 0.f;
#define MV(i,PA,PB,AX,AY) { float4 hv=h4p[i]; \
      f32x2 lo; lo.x=hv.x; lo.y=hv.y; f32x2 hi; hi.x=hv.z; hi.y=hv.w; \
      asm("v_pk_fma_f32 %0, %1, %2, %0" : "+v"(AX) : "v"(PA), "v"(lo)); \
      asm("v_pk_fma_f32 %0, %1, %2, %0" : "+v"(AY) : "v"(PB), "v"(hi)); }
      MV(0,P0,P1,A0,A1)    MV(1,P2,P3,A2,A3)    MV(2,P4,P5,A0,A1)
      MV(3,P6,P7,A2,A3)    MV(4,P8,P9,A0,A1)    MV(5,P10,P11,A2,A3)
      MV(6,P12,P13,A0,A1)  MV(7,P14,P15,A2,A3)  MV(8,P16,P17,A0,A1)
      MV(9,P18,P19,A2,A3)  MV(10,P20,P21,A0,A1) MV(11,P22,P23,A2,A3)
      MV(12,P24,P25,A0,A1) MV(13,P26,P27,A2,A3) MV(14,P28,P29,A0,A1)
      MV(15,P30,P31,A2,A3) MV(16,P32,P33,A0,A1) MV(17,P34,P35,A2,A3)
      MV(18,P36,P37,A0,A1) MV(19,P38,P39,A2,A3) MV(20,P40,P41,A0,A1)
      MV(21,P42,P43,A2,A3) MV(22,P44,P45,A0,A1) MV(23,P46,P47,A2,A3)
      MV(24,P48,P49,A0,A1)
#undef MV
      if (hasX){
        const f32x2* xp2 = (const f32x2*)xst[t&1];
#define MX(i,Un,AX) { f32x2 xv=xp2[i]; \
      asm("v_pk_fma_f32 %0, %1, %2, %0" : "+v"(AX) : "v"(Un), "v"(xv)); }
        MX(0,U0,A2) MX(1,U1,A3) MX(2,U2,A0) MX(3,U3,A1) MX(4,U4,A2)
#undef MX
      }
      a = ((A0.x+A0.y)+(A1.x+A1.y)) + ((A2.x+A2.y)+(A3.x+A3.y));
      if (partIdx>=0 && !hh) part[partIdx][row] = a;
    }

    if (!isA && wv==8 && (s+1)<T){           // poll + stage h2[s+1]
      while (__hip_atomic_load(progp, __ATOMIC_ACQUIRE, __HIP_MEMORY_SCOPE_AGENT) < s+2)
        __builtin_amdgcn_s_sleep(2);
      if (lane<28){
        size_t base = (size_t)(b*ringSlots + ((s+1)&rmask))*112;
        ((float4*)h2l[(s+1)&1])[lane] = ((const float4*)(ring+base))[lane];
      }
      if (lane==0)
        __hip_atomic_store(consp, s+2, __ATOMIC_RELEASE, __HIP_MEMORY_SCOPE_AGENT);
    }
    if (isA && wv==0 && lane<NIN && (s+2)<T)  // x prefetch (2-step lookahead)
      xr = xg[(size_t)b*T*NIN + (size_t)(s+2)*NIN + lane];
    __syncthreads();

    // phase B: finalize / output
    if (act && hh){
      float v = a;
      if (partIdx>=0) v += part[partIdx][row];
      float hval = ftanh(v);
      hb[dstL][t&1][row] = hval;
      if (ringSt && row<H)
        ring[(size_t)(b*ringSlots + (t&rmask))*112 + row] = hval;
      if (t==T-1 && row<H){
        int gl = isA ? dstL : dstL+3;
        outf[hfBase + ((size_t)gl*NB + b)*H + row] = hval;
      }
    }
    if (isOut && act && lane<OUTN){
      const int ph = t&7;                     // named-reg rotation (no alloca)
      y0 = (ph==0)?a:y0;  y1 = (ph==1)?a:y1;
      y2 = (ph==2)?a:y2;  y3 = (ph==3)?a:y3;
      y4 = (ph==4)?a:y4;  y5 = (ph==5)?a:y5;
      y6 = (ph==6)?a:y6;  y7 = (ph==7)?a:y7;
      if (ph==7){
        size_t basei = yBase + (size_t)(t-7)*OUTN + lane;
        outf[basei+0*OUTN]=y0; outf[basei+1*OUTN]=y1;
        outf[basei+2*OUTN]=y2; outf[basei+3*OUTN]=y3;
        outf[basei+4*OUTN]=y4; outf[basei+5*OUTN]=y5;
        outf[basei+6*OUTN]=y6; outf[basei+7*OUTN]=y7;
      }
    }
    if (isA && wv==0 && lane<NIN && (s+2)<T)
      xst[s&1][lane] = xr;                   // slot s&1 == (s+2)&1
    __syncthreads();
  }
  if (isA && wv==0 && lane==0)
    __hip_atomic_store(progp, T, __ATOMIC_RELEASE, __HIP_MEMORY_SCOPE_AGENT);
}

extern "C" void kernel_launch(void* const* d_in, const int* in_sizes, int n_in,
                              void* d_out, int out_size, void* d_ws, size_t ws_size,
                              hipStream_t stream){
  int* flags = (int*)d_ws;                       // 0xAA poison => negative ints
  size_t flagBytes = (size_t)2*NB*32*sizeof(int);
  float* ring = (float*)((char*)d_ws + flagBytes);
  size_t availF = ws_size > flagBytes ? (ws_size - flagBytes)/sizeof(float) : 0;
  int slots = 64;
  while (slots > 2 && (size_t)NB*slots*112 > availF) slots >>= 1;
  rnn5<<<dim3(2*NB), dim3(640), 0, stream>>>(
    (const float*)d_in[0], (const float*)d_in[1], (const float*)d_in[2],
    (const float*)d_in[3], (const float*)d_in[4], (const float*)d_in[5],
    (const float*)d_in[6], (const float*)d_in[7], (const float*)d_in[8],
    (float*)d_out, ring, flags, slots);
}